// Round 4
// baseline (453.172 us; speedup 1.0000x reference)
//
#include <hip/hip_runtime.h>
#include <hip/hip_bf16.h>

#define NODES 32768
#define HD 128
#define NE 524288
#define NR 8

typedef unsigned int u32;
typedef unsigned short u16;
typedef __attribute__((ext_vector_type(8))) short bf16x8;
typedef __attribute__((ext_vector_type(4))) float f32x4;

// ---- ws byte offsets ----
#define XH_OFF   (0u)                      // bf16 hi, 8 MB (reused both layers)
#define XL_OFF   (8u<<20)                  // bf16 lo, 8 MB
#define Y_OFF    (16u<<20)                 // bf16 y[8][NODES][128], 64 MB
#define Z_OFF    (80u<<20)                 // fp32 z[NODES][128], 16 MB
#define ADJ_OFF  (96u<<20)                 // u32 x NE
#define RP_OFF   (98u<<20)                 // u32 x (NODES+1)
#define CUR_OFF  ((98u<<20)+(256u<<10))    // u32 x NODES
#define BSUM_OFF ((98u<<20)+(512u<<10))    // u32 x 128
#define BP_OFF   ((98u<<20)+(640u<<10))    // packed weights bf16: 2 layers x 9 tiles x 2 segs x 16384

#define BP_LAYER 294912                    // 9*2*16384

__device__ __forceinline__ float bflo(u32 u){ union{u32 i;float f;}c; c.i=u<<16; return c.f; }
__device__ __forceinline__ float bfhi(u32 u){ union{u32 i;float f;}c; c.i=u&0xffff0000u; return c.f; }
__device__ __forceinline__ u16 f2bf(float f){
  u32 u=__float_as_uint(f);
  u32 r=u + 0x7fffu + ((u>>16)&1u);
  return (u16)(r>>16);
}
__device__ __forceinline__ float bf2f(u16 h){ return __uint_as_float(((u32)h)<<16); }

__device__ __forceinline__ void gl_lds16(const void* g, void* l){
  __builtin_amdgcn_global_load_lds((const __attribute__((address_space(1))) u32*)g,
                                   (__attribute__((address_space(3))) u32*)l, 16, 0, 0);
}

// ---------------- embed + projection GEMM (fp32 vector) ----------------
__device__ __forceinline__ void fma64(const float* At, const float* Wt,
                                      int mq, int gq, float acc[8][4])
{
#pragma unroll 8
  for(int kk=0;kk<64;kk++){
    const float4 a0=*(const float4*)&At[kk*68+mq*8];
    const float4 a1=*(const float4*)&At[kk*68+mq*8+4];
    const float4 w =*(const float4*)&Wt[kk*132+gq*4];
    float av[8]={a0.x,a0.y,a0.z,a0.w,a1.x,a1.y,a1.z,a1.w};
#pragma unroll
    for(int i=0;i<8;i++){
      acc[i][0]=fmaf(av[i],w.x,acc[i][0]);
      acc[i][1]=fmaf(av[i],w.y,acc[i][1]);
      acc[i][2]=fmaf(av[i],w.z,acc[i][2]);
      acc[i][3]=fmaf(av[i],w.w,acc[i][3]);
    }
  }
}

__global__ __launch_bounds__(256) void embed_gemm(
    const int* __restrict__ cid, const int* __restrict__ kid,
    const float* __restrict__ cemb, const float* __restrict__ kemb,
    const float* __restrict__ pW, const float* __restrict__ pb,
    u16* __restrict__ xh, u16* __restrict__ xl)
{
  __shared__ float At[64*68];
  __shared__ float Wt[64*132];
  const int tid=threadIdx.x;
  const int d0=blockIdx.x*64;
  const int mq=tid>>5, gq=tid&31;
  float acc[8][4];
#pragma unroll
  for(int i=0;i<8;i++){ acc[i][0]=0.f; acc[i][1]=0.f; acc[i][2]=0.f; acc[i][3]=0.f; }

  for(int c=0;c<2;c++){
    const int h0=c*64;
    __syncthreads();
    { int m=tid>>2; int hh=(tid&3)*16;
      int ci=cid[d0+m], ki=kid[d0+m];
      const float* cp=cemb+(size_t)ci*HD+h0+hh;
      const float* kp=kemb+(size_t)ki*HD+h0+hh;
      float* ap=&At[hh*68+m];
#pragma unroll
      for(int j=0;j<16;j+=4){
        float4 a=*(const float4*)(cp+j);
        float4 b=*(const float4*)(kp+j);
        ap[(j+0)*68]=a.x+b.x; ap[(j+1)*68]=a.y+b.y;
        ap[(j+2)*68]=a.z+b.z; ap[(j+3)*68]=a.w+b.w;
      }
    }
    { int g=tid>>1; int hh=(tid&1)*32;
      const float* wp=pW+(size_t)g*HD+h0+hh;
      float* wl=&Wt[hh*132+g];
#pragma unroll
      for(int j=0;j<32;j+=4){
        float4 w=*(const float4*)(wp+j);
        wl[(j+0)*132]=w.x; wl[(j+1)*132]=w.y; wl[(j+2)*132]=w.z; wl[(j+3)*132]=w.w;
      }
    }
    __syncthreads();
    fma64(At,Wt,mq,gq,acc);
  }
  const float4 bias=*(const float4*)&pb[gq*4];
#pragma unroll
  for(int i=0;i<8;i++){
    int m=d0+mq*8+i;
    float v[4]={acc[i][0]+bias.x,acc[i][1]+bias.y,acc[i][2]+bias.z,acc[i][3]+bias.w};
    u16 hb[4], lb[4];
#pragma unroll
    for(int j=0;j<4;j++){ hb[j]=f2bf(v[j]); lb[j]=f2bf(v[j]-bf2f(hb[j])); }
    uint2 hv={(u32)hb[0]|((u32)hb[1]<<16),(u32)hb[2]|((u32)hb[3]<<16)};
    uint2 lv={(u32)lb[0]|((u32)lb[1]<<16),(u32)lb[2]|((u32)lb[3]<<16)};
    *(uint2*)&xh[(size_t)m*HD+gq*4]=hv;
    *(uint2*)&xl[(size_t)m*HD+gq*4]=lv;
  }
}

// ---------------- weight prep: per layer, 9 n-tiles (8 relations + self), hi/lo segs,
// MFMA-fragment-contiguous: k = kc*64 + ks*32 + q*8 + j -> ((kc*2+ks)*128+n)*32 + q*8 + j
__global__ void prep_w(const float* __restrict__ rW, const float* __restrict__ sW,
                       u16* __restrict__ Bp)
{
  int idx=blockIdx.x*256+threadIdx.x;           // 2 * 9 * 16384 = 294912 total
  int l=idx/147456;
  int rem=idx%147456;
  int t=rem>>14;
  int kn=rem&16383;
  int k=kn>>7, n=kn&127;
  float w;
  if(t<8) w=rW[(((size_t)l*NR+t)*HD+n)*HD+k];
  else    w=sW[((size_t)l*HD+n)*HD+k];
  u16* base=Bp+(size_t)l*BP_LAYER+(size_t)t*32768;
  int kc=k>>6, kin=k&63, ks=kin>>5, q=(kin>>3)&3, j=kin&7;
  size_t off=((size_t)(kc*2+ks)*128+n)*32+q*8+j;
  u16 hb=f2bf(w);
  u16 lb=f2bf(w-bf2f(hb));
  base[off]=hb;
  base[off+16384]=lb;
}

// ---------------- CSR build ----------------
__global__ void count_deg(const int* __restrict__ dst, u32* __restrict__ cnt){
  int e=blockIdx.x*256+threadIdx.x;
  atomicAdd(&cnt[dst[e]],1u);
}

__global__ void scan1(const u32* __restrict__ cnt, u32* __restrict__ rp, u32* __restrict__ bsum){
  __shared__ u32 sh[256];
  int t=threadIdx.x; int base=blockIdx.x*256;
  u32 v=cnt[base+t]; sh[t]=v; __syncthreads();
  for(int off=1;off<256;off<<=1){
    u32 tv=(t>=off)?sh[t-off]:0u; __syncthreads();
    sh[t]+=tv; __syncthreads();
  }
  rp[base+t]=sh[t]-v;
  if(t==255) bsum[blockIdx.x]=sh[255];
}

__global__ void scan2(u32* __restrict__ bsum, u32* __restrict__ rp){
  __shared__ u32 sh[128];
  int t=threadIdx.x;
  u32 v=bsum[t]; sh[t]=v; __syncthreads();
  for(int off=1;off<128;off<<=1){
    u32 tv=(t>=off)?sh[t-off]:0u; __syncthreads();
    sh[t]+=tv; __syncthreads();
  }
  bsum[t]=sh[t]-v;
  if(t==0) rp[NODES]=NE;
}

__global__ void scan3(u32* __restrict__ rp, const u32* __restrict__ bsum){
  int i=blockIdx.x*256+threadIdx.x;
  rp[i]+=bsum[blockIdx.x];
}

__global__ void scatter_edges(const int* __restrict__ src, const int* __restrict__ dst,
                              const int* __restrict__ et, const u32* __restrict__ rp,
                              u32* __restrict__ cur, u32* __restrict__ adj){
  int e=blockIdx.x*256+threadIdx.x;
  int d=dst[e];
  u32 pos=atomicAdd(&cur[d],1u);
  adj[rp[d]+pos]=(u32)src[e] | ((u32)et[e]<<16);
}

// ---------------- gemm_y: stage A once, loop all 9 output tiles ----------------
// y[t] = x @ W_t^T (t<8, bf16 out), z = x @ selfW^T (t==8, fp32 out)
// block = 64 rows; 4 waves each own 32 of the 128 output cols; grid NODES/64
__global__ __launch_bounds__(256,2) void gemm_y(
    const u16* __restrict__ xhi, const u16* __restrict__ xlo,
    const u16* __restrict__ Bt, u16* __restrict__ y, float* __restrict__ z)
{
  __shared__ u16 Atile[4][64*64];   // [part*2+c], 8 KB each, 128B rows, 16B-chunk XOR swizzle
  const int tid=threadIdx.x;
  const int wave=tid>>6, lane=tid&63;
  const int q=lane>>4;
  const int d0=blockIdx.x*64;

  const int st_row_in=lane>>3;
  const int st_gj=(lane&7)^(lane>>3);

  // stage all 4 sub-tiles (xhi c0/c1, xlo c0/c1) — one barrier total
#pragma unroll
  for(int part=0;part<2;part++){
    const u16* xs = part? xlo : xhi;
#pragma unroll
    for(int c=0;c<2;c++){
#pragma unroll
      for(int i_=0;i_<2;i_++){
        int r_=wave*16+i_*8+st_row_in;
        const u16* g_=xs+(size_t)(d0+r_)*HD + c*64 + st_gj*8;
        gl_lds16(g_, &Atile[part*2+c][(wave*16+i_*8)*64]);
      }
    }
  }
  __syncthreads();

  // hold xhi fragments in registers for the whole t-loop (64 VGPRs)
  bf16x8 ahi[2][2][4];
#pragma unroll
  for(int c=0;c<2;c++)
#pragma unroll
    for(int ks=0;ks<2;ks++)
#pragma unroll
      for(int tm=0;tm<4;tm++){
        int m=tm*16+(lane&15);
        ahi[c][ks][tm]=*(const bf16x8*)&Atile[c][m*64+(((ks*4)+q)^(m&7))*8];
      }

  const int nbase=wave*32+(lane&15);

  for(int t=0;t<9;t++){
    const u16* Btile=Bt+(size_t)t*32768;
    f32x4 acc[4][2];
#pragma unroll
    for(int tm=0;tm<4;tm++){ acc[tm][0]=(f32x4){0.f,0.f,0.f,0.f}; acc[tm][1]=(f32x4){0.f,0.f,0.f,0.f}; }

    // part 0: xhi @ {Whi, Wlo}
#pragma unroll
    for(int s=0;s<2;s++){
      const u16* Bb=Btile+s*16384;
#pragma unroll
      for(int c=0;c<2;c++)
#pragma unroll
        for(int ks=0;ks<2;ks++)
#pragma unroll
          for(int tn=0;tn<2;tn++){
            bf16x8 bfr=*(const bf16x8*)&Bb[((size_t)(c*2+ks)*128+nbase+tn*16)*32+q*8];
#pragma unroll
            for(int tm=0;tm<4;tm++)
              acc[tm][tn]=__builtin_amdgcn_mfma_f32_16x16x32_bf16(ahi[c][ks][tm],bfr,acc[tm][tn],0,0,0);
          }
    }
    // part 1: xlo @ Whi (A frags re-read from LDS; data still valid)
#pragma unroll
    for(int c=0;c<2;c++)
#pragma unroll
      for(int ks=0;ks<2;ks++){
        bf16x8 alo[4];
#pragma unroll
        for(int tm=0;tm<4;tm++){
          int m=tm*16+(lane&15);
          alo[tm]=*(const bf16x8*)&Atile[2+c][m*64+(((ks*4)+q)^(m&7))*8];
        }
#pragma unroll
        for(int tn=0;tn<2;tn++){
          bf16x8 bfr=*(const bf16x8*)&Btile[((size_t)(c*2+ks)*128+nbase+tn*16)*32+q*8];
#pragma unroll
          for(int tm=0;tm<4;tm++)
            acc[tm][tn]=__builtin_amdgcn_mfma_f32_16x16x32_bf16(alo[tm],bfr,acc[tm][tn],0,0,0);
        }
      }

    // epilogue: C/D layout col=lane&15, row=(lane>>4)*4+reg
    if(t<8){
      u16* yt=y+((size_t)t*NODES+d0)*HD;
#pragma unroll
      for(int tn=0;tn<2;tn++){
        int n=nbase+tn*16;
#pragma unroll
        for(int tm=0;tm<4;tm++){
          int rbase=tm*16+q*4;
#pragma unroll
          for(int r=0;r<4;r++)
            yt[(size_t)(rbase+r)*HD+n]=f2bf(acc[tm][tn][r]);
        }
      }
    } else {
      float* zt=z+(size_t)d0*HD;
#pragma unroll
      for(int tn=0;tn<2;tn++){
        int n=nbase+tn*16;
#pragma unroll
        for(int tm=0;tm<4;tm++){
          int rbase=tm*16+q*4;
#pragma unroll
          for(int r=0;r<4;r++)
            zt[(size_t)(rbase+r)*HD+n]=acc[tm][tn][r];
        }
      }
    }
  }
}

// ---------------- gather_combine: agg = (1/deg) * sum_e y[type][src]; out = relu(z+agg+b)
__global__ __launch_bounds__(256) void gather_combine(
    const u32* __restrict__ y, const float* __restrict__ z,
    const u32* __restrict__ adj, const u32* __restrict__ rp,
    const float* __restrict__ sb, const int* __restrict__ mask,
    u32* __restrict__ xh, u32* __restrict__ xl, float* __restrict__ outf, int last)
{
  const int wave=threadIdx.x>>6, lane=threadIdx.x&63;
  const int node=blockIdx.x*4+wave;
  const int beg=(int)rp[node], end=(int)rp[node+1];
  float a0=0.f, a1=0.f;
  int e=beg;
  for(; e+8<=end; e+=8){
    u32 qv[8], vv[8];
#pragma unroll
    for(int i=0;i<8;i++) qv[i]=adj[e+i];
#pragma unroll
    for(int i=0;i<8;i++) vv[i]=y[((size_t)(qv[i]>>16)*NODES+(qv[i]&0x7fffu))*64+lane];
#pragma unroll
    for(int i=0;i<8;i++){ a0+=bflo(vv[i]); a1+=bfhi(vv[i]); }
  }
  for(; e<end; ++e){
    u32 qq=adj[e];
    u32 v=y[((size_t)(qq>>16)*NODES+(qq&0x7fffu))*64+lane];
    a0+=bflo(v); a1+=bfhi(v);
  }
  float inv=1.f/fmaxf((float)(end-beg),1.f);
  float2 zz=*(const float2*)&z[(size_t)node*HD+2*lane];
  float2 bb=*(const float2*)&sb[2*lane];
  float v0=fmaxf(zz.x+a0*inv+bb.x,0.f);
  float v1=fmaxf(zz.y+a1*inv+bb.y,0.f);
  if(last){
    float mk=(float)mask[node];
    float2 o={v0*mk,v1*mk};
    *(float2*)&outf[(size_t)node*HD+2*lane]=o;
  } else {
    u16 h0=f2bf(v0), h1=f2bf(v1);
    u16 l0=f2bf(v0-bf2f(h0)), l1=f2bf(v1-bf2f(h1));
    xh[(size_t)node*64+lane]=(u32)h0|((u32)h1<<16);
    xl[(size_t)node*64+lane]=(u32)l0|((u32)l1<<16);
  }
}

extern "C" void kernel_launch(void* const* d_in, const int* in_sizes, int n_in,
                              void* d_out, int out_size, void* d_ws, size_t ws_size,
                              hipStream_t stream)
{
  (void)in_sizes; (void)n_in; (void)out_size; (void)ws_size;
  const int*   cid =(const int*)  d_in[0];
  const int*   kid =(const int*)  d_in[1];
  const int*   mask=(const int*)  d_in[2];
  const int*   ei  =(const int*)  d_in[3];
  const int*   et  =(const int*)  d_in[4];
  const float* cemb=(const float*)d_in[5];
  const float* kemb=(const float*)d_in[6];
  const float* pW  =(const float*)d_in[7];
  const float* pb  =(const float*)d_in[8];
  const float* sW  =(const float*)d_in[9];
  const float* sb  =(const float*)d_in[10];
  const float* rW  =(const float*)d_in[11];
  float* out=(float*)d_out;
  char*  ws =(char*)d_ws;

  u16* xh =(u16*)(ws+XH_OFF);
  u16* xl =(u16*)(ws+XL_OFF);
  u16* y  =(u16*)(ws+Y_OFF);
  float* z=(float*)(ws+Z_OFF);
  u32* adj =(u32*)(ws+ADJ_OFF);
  u32* rp  =(u32*)(ws+RP_OFF);
  u32* cur =(u32*)(ws+CUR_OFF);
  u32* bsum=(u32*)(ws+BSUM_OFF);
  u16* Bp  =(u16*)(ws+BP_OFF);
  const int* srcA=ei;
  const int* dstA=ei+NE;

  hipMemsetAsync(cur,0,NODES*sizeof(u32),stream);
  prep_w<<<1152,256,0,stream>>>(rW,sW,Bp);
  embed_gemm<<<NODES/64,256,0,stream>>>(cid,kid,cemb,kemb,pW,pb,xh,xl);
  count_deg<<<NE/256,256,0,stream>>>(dstA,cur);
  scan1<<<NODES/256,256,0,stream>>>(cur,rp,bsum);
  scan2<<<1,128,0,stream>>>(bsum,rp);
  scan3<<<NODES/256,256,0,stream>>>(rp,bsum);
  hipMemsetAsync(cur,0,NODES*sizeof(u32),stream);
  scatter_edges<<<NE/256,256,0,stream>>>(srcA,dstA,et,rp,cur,adj);

  // layer 0
  gemm_y<<<NODES/64,256,0,stream>>>(xh,xl,Bp,y,z);
  gather_combine<<<NODES/4,256,0,stream>>>((const u32*)y,z,adj,rp,sb,mask,(u32*)xh,(u32*)xl,out,0);
  // layer 1
  gemm_y<<<NODES/64,256,0,stream>>>(xh,xl,Bp+BP_LAYER,y,z);
  gather_combine<<<NODES/4,256,0,stream>>>((const u32*)y,z,adj,rp,sb+HD,mask,(u32*)xh,(u32*)xl,out,1);
}

// Round 5
// 343.064 us; speedup vs baseline: 1.3210x; 1.3210x over previous
//
#include <hip/hip_runtime.h>
#include <hip/hip_bf16.h>

#define NODES 32768
#define HD 128
#define NE 524288
#define NR 8

typedef unsigned int u32;
typedef unsigned short u16;
typedef __attribute__((ext_vector_type(8))) short bf16x8;
typedef __attribute__((ext_vector_type(4))) float f32x4;

// ---- ws byte offsets ----
#define XH_OFF   (0u)                      // bf16 hi, 8 MB (reused both layers)
#define XL_OFF   (8u<<20)                  // bf16 lo, 8 MB
#define Y_OFF    (16u<<20)                 // bf16 y[8][NODES][128], 64 MB
#define Z_OFF    (80u<<20)                 // fp32 z[NODES][128], 16 MB
#define ADJ_OFF  (96u<<20)                 // u32 x NE
#define RP_OFF   (98u<<20)                 // u32 x (NODES+1)
#define CUR_OFF  ((98u<<20)+(256u<<10))    // u32 x NODES
#define BSUM_OFF ((98u<<20)+(512u<<10))    // u32 x 128
#define BP_OFF   ((98u<<20)+(640u<<10))    // packed weights bf16: 2 layers x 9 tiles x 2 segs x 16384

#define BP_LAYER 294912                    // 9*2*16384

__device__ __forceinline__ float bflo(u32 u){ union{u32 i;float f;}c; c.i=u<<16; return c.f; }
__device__ __forceinline__ float bfhi(u32 u){ union{u32 i;float f;}c; c.i=u&0xffff0000u; return c.f; }
__device__ __forceinline__ u16 f2bf(float f){
  u32 u=__float_as_uint(f);
  u32 r=u + 0x7fffu + ((u>>16)&1u);
  return (u16)(r>>16);
}
__device__ __forceinline__ float bf2f(u16 h){ return __uint_as_float(((u32)h)<<16); }

__device__ __forceinline__ void gl_lds16(const void* g, void* l){
  __builtin_amdgcn_global_load_lds((const __attribute__((address_space(1))) u32*)g,
                                   (__attribute__((address_space(3))) u32*)l, 16, 0, 0);
}

// ---------------- embed + projection GEMM (fp32 vector) ----------------
__device__ __forceinline__ void fma64(const float* At, const float* Wt,
                                      int mq, int gq, float acc[8][4])
{
#pragma unroll 8
  for(int kk=0;kk<64;kk++){
    const float4 a0=*(const float4*)&At[kk*68+mq*8];
    const float4 a1=*(const float4*)&At[kk*68+mq*8+4];
    const float4 w =*(const float4*)&Wt[kk*132+gq*4];
    float av[8]={a0.x,a0.y,a0.z,a0.w,a1.x,a1.y,a1.z,a1.w};
#pragma unroll
    for(int i=0;i<8;i++){
      acc[i][0]=fmaf(av[i],w.x,acc[i][0]);
      acc[i][1]=fmaf(av[i],w.y,acc[i][1]);
      acc[i][2]=fmaf(av[i],w.z,acc[i][2]);
      acc[i][3]=fmaf(av[i],w.w,acc[i][3]);
    }
  }
}

__global__ __launch_bounds__(256) void embed_gemm(
    const int* __restrict__ cid, const int* __restrict__ kid,
    const float* __restrict__ cemb, const float* __restrict__ kemb,
    const float* __restrict__ pW, const float* __restrict__ pb,
    u16* __restrict__ xh, u16* __restrict__ xl)
{
  __shared__ float At[64*68];
  __shared__ float Wt[64*132];
  const int tid=threadIdx.x;
  const int d0=blockIdx.x*64;
  const int mq=tid>>5, gq=tid&31;
  float acc[8][4];
#pragma unroll
  for(int i=0;i<8;i++){ acc[i][0]=0.f; acc[i][1]=0.f; acc[i][2]=0.f; acc[i][3]=0.f; }

  for(int c=0;c<2;c++){
    const int h0=c*64;
    __syncthreads();
    { int m=tid>>2; int hh=(tid&3)*16;
      int ci=cid[d0+m], ki=kid[d0+m];
      const float* cp=cemb+(size_t)ci*HD+h0+hh;
      const float* kp=kemb+(size_t)ki*HD+h0+hh;
      float* ap=&At[hh*68+m];
#pragma unroll
      for(int j=0;j<16;j+=4){
        float4 a=*(const float4*)(cp+j);
        float4 b=*(const float4*)(kp+j);
        ap[(j+0)*68]=a.x+b.x; ap[(j+1)*68]=a.y+b.y;
        ap[(j+2)*68]=a.z+b.z; ap[(j+3)*68]=a.w+b.w;
      }
    }
    { int g=tid>>1; int hh=(tid&1)*32;
      const float* wp=pW+(size_t)g*HD+h0+hh;
      float* wl=&Wt[hh*132+g];
#pragma unroll
      for(int j=0;j<32;j+=4){
        float4 w=*(const float4*)(wp+j);
        wl[(j+0)*132]=w.x; wl[(j+1)*132]=w.y; wl[(j+2)*132]=w.z; wl[(j+3)*132]=w.w;
      }
    }
    __syncthreads();
    fma64(At,Wt,mq,gq,acc);
  }
  const float4 bias=*(const float4*)&pb[gq*4];
#pragma unroll
  for(int i=0;i<8;i++){
    int m=d0+mq*8+i;
    float v[4]={acc[i][0]+bias.x,acc[i][1]+bias.y,acc[i][2]+bias.z,acc[i][3]+bias.w};
    u16 hb[4], lb[4];
#pragma unroll
    for(int j=0;j<4;j++){ hb[j]=f2bf(v[j]); lb[j]=f2bf(v[j]-bf2f(hb[j])); }
    uint2 hv={(u32)hb[0]|((u32)hb[1]<<16),(u32)hb[2]|((u32)hb[3]<<16)};
    uint2 lv={(u32)lb[0]|((u32)lb[1]<<16),(u32)lb[2]|((u32)lb[3]<<16)};
    *(uint2*)&xh[(size_t)m*HD+gq*4]=hv;
    *(uint2*)&xl[(size_t)m*HD+gq*4]=lv;
  }
}

// ---------------- weight prep: per layer, 9 n-tiles (8 relations + self), hi/lo segs,
// MFMA-fragment-contiguous: k = ks32*32 + q*8 + j -> (ks32*128+n)*32 + q*8 + j
__global__ void prep_w(const float* __restrict__ rW, const float* __restrict__ sW,
                       u16* __restrict__ Bp)
{
  int idx=blockIdx.x*256+threadIdx.x;           // 2 * 9 * 16384 = 294912 total
  int l=idx/147456;
  int rem=idx%147456;
  int t=rem>>14;
  int kn=rem&16383;
  int k=kn>>7, n=kn&127;
  float w;
  if(t<8) w=rW[(((size_t)l*NR+t)*HD+n)*HD+k];
  else    w=sW[((size_t)l*HD+n)*HD+k];
  u16* base=Bp+(size_t)l*BP_LAYER+(size_t)t*32768;
  int ks=k>>5, q=(k>>3)&3, j=k&7;
  size_t off=((size_t)ks*128+n)*32+q*8+j;
  u16 hb=f2bf(w);
  u16 lb=f2bf(w-bf2f(hb));
  base[off]=hb;
  base[off+16384]=lb;
}

// ---------------- CSR build ----------------
__global__ void count_deg(const int* __restrict__ dst, u32* __restrict__ cnt){
  int e=blockIdx.x*256+threadIdx.x;
  atomicAdd(&cnt[dst[e]],1u);
}

__global__ void scan1(const u32* __restrict__ cnt, u32* __restrict__ rp, u32* __restrict__ bsum){
  __shared__ u32 sh[256];
  int t=threadIdx.x; int base=blockIdx.x*256;
  u32 v=cnt[base+t]; sh[t]=v; __syncthreads();
  for(int off=1;off<256;off<<=1){
    u32 tv=(t>=off)?sh[t-off]:0u; __syncthreads();
    sh[t]+=tv; __syncthreads();
  }
  rp[base+t]=sh[t]-v;
  if(t==255) bsum[blockIdx.x]=sh[255];
}

__global__ void scan2(u32* __restrict__ bsum, u32* __restrict__ rp){
  __shared__ u32 sh[128];
  int t=threadIdx.x;
  u32 v=bsum[t]; sh[t]=v; __syncthreads();
  for(int off=1;off<128;off<<=1){
    u32 tv=(t>=off)?sh[t-off]:0u; __syncthreads();
    sh[t]+=tv; __syncthreads();
  }
  bsum[t]=sh[t]-v;
  if(t==0) rp[NODES]=NE;
}

__global__ void scan3(u32* __restrict__ rp, const u32* __restrict__ bsum){
  int i=blockIdx.x*256+threadIdx.x;
  rp[i]+=bsum[blockIdx.x];
}

__global__ void scatter_edges(const int* __restrict__ src, const int* __restrict__ dst,
                              const int* __restrict__ et, const u32* __restrict__ rp,
                              u32* __restrict__ cur, u32* __restrict__ adj){
  int e=blockIdx.x*256+threadIdx.x;
  int d=dst[e];
  u32 pos=atomicAdd(&cur[d],1u);
  adj[rp[d]+pos]=(u32)src[e] | ((u32)et[e]<<16);
}

// ---------------- gemm_y: 128x128 tile, one t per block, 2 staging phases ----------------
// y[t] = x @ W_t^T (t<8, bf16 out), z = x @ selfW^T (t==8, fp32 out)
// grid (NODES/128, 9); waves 2x2; Atile holds full K=128 of one x-part (32 KB, 1 barrier)
__global__ __launch_bounds__(256,3) void gemm_y(
    const u16* __restrict__ xhi, const u16* __restrict__ xlo,
    const u16* __restrict__ Bt, u16* __restrict__ y, float* __restrict__ z)
{
  __shared__ u16 Atile[128*128];   // 32 KB; row=256B, 16B-chunk XOR-16 swizzle
  const int tid=threadIdx.x;
  const int wave=tid>>6, lane=tid&63;
  const int wm=wave>>1, wn=wave&1;
  const int q=lane>>4;
  const int d0=blockIdx.x*128;
  const int t=blockIdx.y;
  const u16* Btile=Bt+(size_t)t*32768;

  f32x4 acc[4][4];
#pragma unroll
  for(int a=0;a<4;a++)
#pragma unroll
    for(int b=0;b<4;b++) acc[a][b]=(f32x4){0.f,0.f,0.f,0.f};

  const int st_c  = lane&15;        // dest 16B chunk within row
  const int st_rin= lane>>4;        // row within 4-row issue

  // ---- stage xhi (whole 128x128), one barrier ----
#pragma unroll
  for(int i=0;i<8;i++){
    int rbase=wave*32+i*4;
    int r=rbase+st_rin;
    int g=st_c ^ (r&15);
    gl_lds16(xhi+(size_t)(d0+r)*HD+g*8, &Atile[rbase*128]);
  }
  __syncthreads();

  // ---- part 0: xhi @ {Whi, Wlo} ----
#pragma unroll
  for(int ks=0;ks<4;ks++){
    bf16x8 afr[4];
#pragma unroll
    for(int tm=0;tm<4;tm++){
      int m=wm*64+tm*16+(lane&15);
      afr[tm]=*(const bf16x8*)&Atile[m*128+(((ks*4)+q)^(m&15))*8];
    }
#pragma unroll
    for(int s=0;s<2;s++){
      const u16* Bb=Btile+s*16384;
#pragma unroll
      for(int tn=0;tn<4;tn++){
        int n=wn*64+tn*16+(lane&15);
        bf16x8 bfr=*(const bf16x8*)&Bb[((size_t)ks*128+n)*32+q*8];
#pragma unroll
        for(int tm=0;tm<4;tm++)
          acc[tm][tn]=__builtin_amdgcn_mfma_f32_16x16x32_bf16(afr[tm],bfr,acc[tm][tn],0,0,0);
      }
    }
  }

  // ---- restage xlo, part 1: xlo @ Whi ----
  __syncthreads();
#pragma unroll
  for(int i=0;i<8;i++){
    int rbase=wave*32+i*4;
    int r=rbase+st_rin;
    int g=st_c ^ (r&15);
    gl_lds16(xlo+(size_t)(d0+r)*HD+g*8, &Atile[rbase*128]);
  }
  __syncthreads();

#pragma unroll
  for(int ks=0;ks<4;ks++){
    bf16x8 afr[4];
#pragma unroll
    for(int tm=0;tm<4;tm++){
      int m=wm*64+tm*16+(lane&15);
      afr[tm]=*(const bf16x8*)&Atile[m*128+(((ks*4)+q)^(m&15))*8];
    }
#pragma unroll
    for(int tn=0;tn<4;tn++){
      int n=wn*64+tn*16+(lane&15);
      bf16x8 bfr=*(const bf16x8*)&Btile[((size_t)ks*128+n)*32+q*8];
#pragma unroll
      for(int tm=0;tm<4;tm++)
        acc[tm][tn]=__builtin_amdgcn_mfma_f32_16x16x32_bf16(afr[tm],bfr,acc[tm][tn],0,0,0);
    }
  }

  // ---- epilogue: C/D layout col=lane&15, row=(lane>>4)*4+reg ----
  if(t<8){
    u16* yt=y+((size_t)t*NODES+d0)*HD;
#pragma unroll
    for(int tn=0;tn<4;tn++){
      int n=wn*64+tn*16+(lane&15);
#pragma unroll
      for(int tm=0;tm<4;tm++){
        int rbase=wm*64+tm*16+q*4;
#pragma unroll
        for(int r=0;r<4;r++)
          yt[(size_t)(rbase+r)*HD+n]=f2bf(acc[tm][tn][r]);
      }
    }
  } else {
    float* zt=z+(size_t)d0*HD;
#pragma unroll
    for(int tn=0;tn<4;tn++){
      int n=wn*64+tn*16+(lane&15);
#pragma unroll
      for(int tm=0;tm<4;tm++){
        int rbase=wm*64+tm*16+q*4;
#pragma unroll
        for(int r=0;r<4;r++)
          zt[(size_t)(rbase+r)*HD+n]=acc[tm][tn][r];
      }
    }
  }
}

// ---------------- gather_combine: agg = (1/deg) * sum_e y[type][src]; out = relu(z+agg+b)
__global__ __launch_bounds__(256) void gather_combine(
    const u32* __restrict__ y, const float* __restrict__ z,
    const u32* __restrict__ adj, const u32* __restrict__ rp,
    const float* __restrict__ sb, const int* __restrict__ mask,
    u32* __restrict__ xh, u32* __restrict__ xl, float* __restrict__ outf, int last)
{
  const int wave=threadIdx.x>>6, lane=threadIdx.x&63;
  const int node=blockIdx.x*4+wave;
  const int beg=(int)rp[node], end=(int)rp[node+1];
  float a0=0.f, a1=0.f;
  int e=beg;
  for(; e+8<=end; e+=8){
    u32 qv[8], vv[8];
#pragma unroll
    for(int i=0;i<8;i++) qv[i]=adj[e+i];
#pragma unroll
    for(int i=0;i<8;i++) vv[i]=y[((size_t)(qv[i]>>16)*NODES+(qv[i]&0x7fffu))*64+lane];
#pragma unroll
    for(int i=0;i<8;i++){ a0+=bflo(vv[i]); a1+=bfhi(vv[i]); }
  }
  for(; e<end; ++e){
    u32 qq=adj[e];
    u32 v=y[((size_t)(qq>>16)*NODES+(qq&0x7fffu))*64+lane];
    a0+=bflo(v); a1+=bfhi(v);
  }
  float inv=1.f/fmaxf((float)(end-beg),1.f);
  float2 zz=*(const float2*)&z[(size_t)node*HD+2*lane];
  float2 bb=*(const float2*)&sb[2*lane];
  float v0=fmaxf(zz.x+a0*inv+bb.x,0.f);
  float v1=fmaxf(zz.y+a1*inv+bb.y,0.f);
  if(last){
    float mk=(float)mask[node];
    float2 o={v0*mk,v1*mk};
    *(float2*)&outf[(size_t)node*HD+2*lane]=o;
  } else {
    u16 h0=f2bf(v0), h1=f2bf(v1);
    u16 l0=f2bf(v0-bf2f(h0)), l1=f2bf(v1-bf2f(h1));
    xh[(size_t)node*64+lane]=(u32)h0|((u32)h1<<16);
    xl[(size_t)node*64+lane]=(u32)l0|((u32)l1<<16);
  }
}

extern "C" void kernel_launch(void* const* d_in, const int* in_sizes, int n_in,
                              void* d_out, int out_size, void* d_ws, size_t ws_size,
                              hipStream_t stream)
{
  (void)in_sizes; (void)n_in; (void)out_size; (void)ws_size;
  const int*   cid =(const int*)  d_in[0];
  const int*   kid =(const int*)  d_in[1];
  const int*   mask=(const int*)  d_in[2];
  const int*   ei  =(const int*)  d_in[3];
  const int*   et  =(const int*)  d_in[4];
  const float* cemb=(const float*)d_in[5];
  const float* kemb=(const float*)d_in[6];
  const float* pW  =(const float*)d_in[7];
  const float* pb  =(const float*)d_in[8];
  const float* sW  =(const float*)d_in[9];
  const float* sb  =(const float*)d_in[10];
  const float* rW  =(const float*)d_in[11];
  float* out=(float*)d_out;
  char*  ws =(char*)d_ws;

  u16* xh =(u16*)(ws+XH_OFF);
  u16* xl =(u16*)(ws+XL_OFF);
  u16* y  =(u16*)(ws+Y_OFF);
  float* z=(float*)(ws+Z_OFF);
  u32* adj =(u32*)(ws+ADJ_OFF);
  u32* rp  =(u32*)(ws+RP_OFF);
  u32* cur =(u32*)(ws+CUR_OFF);
  u32* bsum=(u32*)(ws+BSUM_OFF);
  u16* Bp  =(u16*)(ws+BP_OFF);
  const int* srcA=ei;
  const int* dstA=ei+NE;

  hipMemsetAsync(cur,0,NODES*sizeof(u32),stream);
  prep_w<<<1152,256,0,stream>>>(rW,sW,Bp);
  embed_gemm<<<NODES/64,256,0,stream>>>(cid,kid,cemb,kemb,pW,pb,xh,xl);
  count_deg<<<NE/256,256,0,stream>>>(dstA,cur);
  scan1<<<NODES/256,256,0,stream>>>(cur,rp,bsum);
  scan2<<<1,128,0,stream>>>(bsum,rp);
  scan3<<<NODES/256,256,0,stream>>>(rp,bsum);
  hipMemsetAsync(cur,0,NODES*sizeof(u32),stream);
  scatter_edges<<<NE/256,256,0,stream>>>(srcA,dstA,et,rp,cur,adj);

  // layer 0
  gemm_y<<<dim3(NODES/128,9),256,0,stream>>>(xh,xl,Bp,y,z);
  gather_combine<<<NODES/4,256,0,stream>>>((const u32*)y,z,adj,rp,sb,mask,(u32*)xh,(u32*)xl,out,0);
  // layer 1
  gemm_y<<<dim3(NODES/128,9),256,0,stream>>>(xh,xl,Bp+BP_LAYER,y,z);
  gather_combine<<<NODES/4,256,0,stream>>>((const u32*)y,z,adj,rp,sb+HD,mask,(u32*)xh,(u32*)xl,out,1);
}